// Round 1
// baseline (6819.321 us; speedup 1.0000x reference)
//
#include <hip/hip_runtime.h>

// ---------------------------------------------------------------------------
// KPlexPool: GCN -> pools -> matrix-free pooled GCN -> MLP head + softmax
// Sizes: N=100000, E=1600000, H=128, M=150000, KC=60000, B=64, C_OUT=10
// ---------------------------------------------------------------------------

#define H 128

__device__ __forceinline__ void atomAddF(float* p, float v) {
    unsafeAtomicAdd(p, v);   // global_atomic_add_f32 on gfx950
}
__device__ __forceinline__ void atomMaxPos(float* p, float v) {
    // valid for non-negative floats (bit pattern order == numeric order)
    atomicMax(reinterpret_cast<int*>(p), __float_as_int(v));
}

// ---- degree accumulation: deg[dst[e]] += w[e] ------------------------------
__global__ void deg_edges(const int* __restrict__ dst, const float* __restrict__ w,
                          float* __restrict__ deg, int E) {
    int e = blockIdx.x * blockDim.x + threadIdx.x;
    if (e < E) atomAddF(&deg[dst[e]], w[e]);
}

// ---- x = rsqrt(x + 1) ------------------------------------------------------
__global__ void rsqrt_inplace(float* __restrict__ p, int n) {
    int i = blockIdx.x * blockDim.x + threadIdx.x;
    if (i < n) p[i] = rsqrtf(p[i] + 1.0f);
}

// ---- GEMM: Out[r][c] (+)= rowscale[r] * sum_k X[r][k] * W[k][c],  K=128 ----
// 64 rows x 128 cols per block, 256 threads, thread = 4 rows x 8 cols.
// W (64KB) staged in LDS; X rows read through L1 (broadcast within lane group).
__global__ __launch_bounds__(256) void gemm128(
    const float* __restrict__ X, const float* __restrict__ W,
    float* __restrict__ Out, int nrows,
    const float* __restrict__ rowscale, int accumulate)
{
    __shared__ float Wl[128 * 128];
    int t = threadIdx.x;
    for (int i = t; i < 4096; i += 256)
        ((float4*)Wl)[i] = ((const float4*)W)[i];
    __syncthreads();

    int cgrp = t & 15;          // 16 col groups of 8 cols
    int rgrp = t >> 4;          // 16 row groups of 4 rows
    long rb = (long)blockIdx.x * 64 + rgrp * 4;
    long nm1 = (long)nrows - 1;
    const float* xr0 = X + (rb + 0 < nm1 ? rb + 0 : nm1) * H;
    const float* xr1 = X + (rb + 1 < nm1 ? rb + 1 : nm1) * H;
    const float* xr2 = X + (rb + 2 < nm1 ? rb + 2 : nm1) * H;
    const float* xr3 = X + (rb + 3 < nm1 ? rb + 3 : nm1) * H;

    float acc[4][8];
#pragma unroll
    for (int i = 0; i < 4; ++i)
#pragma unroll
        for (int j = 0; j < 8; ++j) acc[i][j] = 0.f;

    for (int k = 0; k < 128; ++k) {
        float4 w0 = ((float4*)Wl)[k * 32 + cgrp * 2];
        float4 w1 = ((float4*)Wl)[k * 32 + cgrp * 2 + 1];
        float xv0 = xr0[k], xv1 = xr1[k], xv2 = xr2[k], xv3 = xr3[k];
        acc[0][0] += xv0 * w0.x; acc[0][1] += xv0 * w0.y; acc[0][2] += xv0 * w0.z; acc[0][3] += xv0 * w0.w;
        acc[0][4] += xv0 * w1.x; acc[0][5] += xv0 * w1.y; acc[0][6] += xv0 * w1.z; acc[0][7] += xv0 * w1.w;
        acc[1][0] += xv1 * w0.x; acc[1][1] += xv1 * w0.y; acc[1][2] += xv1 * w0.z; acc[1][3] += xv1 * w0.w;
        acc[1][4] += xv1 * w1.x; acc[1][5] += xv1 * w1.y; acc[1][6] += xv1 * w1.z; acc[1][7] += xv1 * w1.w;
        acc[2][0] += xv2 * w0.x; acc[2][1] += xv2 * w0.y; acc[2][2] += xv2 * w0.z; acc[2][3] += xv2 * w0.w;
        acc[2][4] += xv2 * w1.x; acc[2][5] += xv2 * w1.y; acc[2][6] += xv2 * w1.z; acc[2][7] += xv2 * w1.w;
        acc[3][0] += xv3 * w0.x; acc[3][1] += xv3 * w0.y; acc[3][2] += xv3 * w0.z; acc[3][3] += xv3 * w0.w;
        acc[3][4] += xv3 * w1.x; acc[3][5] += xv3 * w1.y; acc[3][6] += xv3 * w1.z; acc[3][7] += xv3 * w1.w;
    }

#pragma unroll
    for (int i = 0; i < 4; ++i) {
        long gr = rb + i;
        if (gr >= nrows) continue;
        float* o = Out + gr * H + cgrp * 8;
        float4 o0 = make_float4(acc[i][0], acc[i][1], acc[i][2], acc[i][3]);
        float4 o1 = make_float4(acc[i][4], acc[i][5], acc[i][6], acc[i][7]);
        if (accumulate) {
            float4 p0 = ((float4*)o)[0], p1 = ((float4*)o)[1];
            o0.x += p0.x; o0.y += p0.y; o0.z += p0.z; o0.w += p0.w;
            o1.x += p1.x; o1.y += p1.y; o1.z += p1.z; o1.w += p1.w;
        }
        if (rowscale) {
            float s = rowscale[gr];
            o0.x *= s; o0.y *= s; o0.z *= s; o0.w *= s;
            o1.x *= s; o1.y *= s; o1.z *= s; o1.w *= s;
        }
        ((float4*)o)[0] = o0;
        ((float4*)o)[1] = o1;
    }
}

// ---- agg[n][:] = dinv[n]^2 * xw[n][:]  (float4 granularity) ----------------
__global__ void agg_init(const float* __restrict__ xw, const float* __restrict__ dinv,
                         float* __restrict__ agg, long n4) {
    long i = (long)blockIdx.x * blockDim.x + threadIdx.x;
    if (i >= n4) return;
    float d = dinv[i >> 5];
    float dd = d * d;
    float4 v = ((const float4*)xw)[i];
    ((float4*)agg)[i] = make_float4(dd * v.x, dd * v.y, dd * v.z, dd * v.w);
}

// ---- per edge: Acc[dst] += scale * X[src], scale = w (*dinv[s]*dinv[d]) ----
// 32 lanes / edge, float4 per lane
__global__ __launch_bounds__(256) void edge_msg(
    const int* __restrict__ src, const int* __restrict__ dst,
    const float* __restrict__ w, const float* __restrict__ dinv,
    const float* __restrict__ X, float* __restrict__ Acc, int E, int use_dinv)
{
    int e = blockIdx.x * 8 + (threadIdx.x >> 5);
    if (e >= E) return;
    int lane = threadIdx.x & 31;
    int s = src[e], d = dst[e];
    float sc = w[e];
    if (use_dinv) sc *= dinv[s] * dinv[d];
    float4 v = *(const float4*)(X + (long)s * H + lane * 4);
    float* o = Acc + (long)d * H + lane * 4;
    atomAddF(o + 0, sc * v.x);
    atomAddF(o + 1, sc * v.y);
    atomAddF(o + 2, sc * v.z);
    atomAddF(o + 3, sc * v.w);
}

// ---- h = relu(h + bias) ----------------------------------------------------
__global__ void relu_bias(float* __restrict__ h, const float* __restrict__ bias, long n4) {
    long i = (long)blockIdx.x * blockDim.x + threadIdx.x;
    if (i >= n4) return;
    float4 b = ((const float4*)bias)[i & 31];
    float4 v = ((float4*)h)[i];
    v.x = fmaxf(v.x + b.x, 0.f); v.y = fmaxf(v.y + b.y, 0.f);
    v.z = fmaxf(v.z + b.z, 0.f); v.w = fmaxf(v.w + b.w, 0.f);
    ((float4*)h)[i] = v;
}

// ---- per pair: Aadd[idst] += X[isrc]; Amax[idst] = max(.., X[isrc]) --------
__global__ __launch_bounds__(256) void pair_msg(
    const int* __restrict__ isrc, const int* __restrict__ idst,
    const float* __restrict__ X, float* __restrict__ Aadd,
    float* __restrict__ Amax, int M)
{
    int p = blockIdx.x * 8 + (threadIdx.x >> 5);
    if (p >= M) return;
    int lane = threadIdx.x & 31;
    int s = isrc[p], d = idst[p];
    float4 v = *(const float4*)(X + (long)s * H + lane * 4);
    float* o = Aadd + (long)d * H + lane * 4;
    atomAddF(o + 0, v.x); atomAddF(o + 1, v.y);
    atomAddF(o + 2, v.z); atomAddF(o + 3, v.w);
    if (Amax) {
        float* om = Amax + (long)d * H + lane * 4;
        atomMaxPos(om + 0, v.x); atomMaxPos(om + 1, v.y);
        atomMaxPos(om + 2, v.z); atomMaxPos(om + 3, v.w);
    }
}

// ---- sorted-segment pool: sums + maxes of X rows into Z[b*512 + off + j] ---
// seg is sorted; one block handles a contiguous chunk of rows, thread = col.
__global__ __launch_bounds__(128) void seg_pool(
    const float* __restrict__ X, const int* __restrict__ seg,
    float* __restrict__ Z, int n, int sumoff, int maxoff)
{
    int j = threadIdx.x;
    long beg = (long)blockIdx.x * n / gridDim.x;
    long end = (long)(blockIdx.x + 1) * n / gridDim.x;
    if (beg >= end) return;
    int curb = seg[beg];
    float s = 0.f, mx = 0.f;
    for (long i = beg; i < end; ++i) {
        int b = seg[i];
        if (b != curb) {
            atomAddF(&Z[(long)curb * 512 + sumoff + j], s);
            atomMaxPos(&Z[(long)curb * 512 + maxoff + j], mx);
            s = 0.f; mx = 0.f; curb = b;
        }
        float v = X[i * (long)H + j];
        s += v; mx = fmaxf(mx, v);
    }
    atomAddF(&Z[(long)curb * 512 + sumoff + j], s);
    atomMaxPos(&Z[(long)curb * 512 + maxoff + j], mx);
}

// ---- histogram of seg values into cc (float counts) ------------------------
__global__ void hist64(const int* __restrict__ seg, float* __restrict__ cc, int n) {
    __shared__ int hc[128];
    if (threadIdx.x < 128) hc[threadIdx.x] = 0;
    __syncthreads();
    for (int i = blockIdx.x * blockDim.x + threadIdx.x; i < n; i += gridDim.x * blockDim.x)
        atomicAdd(&hc[seg[i]], 1);
    __syncthreads();
    if (threadIdx.x < 128 && hc[threadIdx.x] != 0)
        atomAddF(&cc[threadIdx.x], (float)hc[threadIdx.x]);
}

// ---- scalar pair/edge kernels for degp -------------------------------------
__global__ void zn1_pairs(const int* __restrict__ nodes, float* __restrict__ zn1, int M) {
    int p = blockIdx.x * blockDim.x + threadIdx.x;
    if (p < M) atomAddF(&zn1[nodes[p]], 1.0f);
}
__global__ void ye1_edges(const int* __restrict__ src, const int* __restrict__ dst,
                          const float* __restrict__ w, const float* __restrict__ zn1,
                          float* __restrict__ ye1, int E) {
    int e = blockIdx.x * blockDim.x + threadIdx.x;
    if (e < E) atomAddF(&ye1[dst[e]], w[e] * zn1[src[e]]);
}
__global__ void degp_pairs(const int* __restrict__ nodes, const int* __restrict__ clus,
                           const float* __restrict__ ye1, float* __restrict__ degp, int M) {
    int p = blockIdx.x * blockDim.x + threadIdx.x;
    if (p < M) atomAddF(&degp[clus[p]], ye1[nodes[p]]);
}

// ---- hp = relu(dinvp[r] * (ap + xws) + b_blk), in place over ap ------------
__global__ void hp_kernel(float* __restrict__ ap, const float* __restrict__ xws,
                          const float* __restrict__ dinvp, const float* __restrict__ bias,
                          long n4) {
    long i = (long)blockIdx.x * blockDim.x + threadIdx.x;
    if (i >= n4) return;
    float d = dinvp[i >> 5];
    float4 b = ((const float4*)bias)[i & 31];
    float4 a = ((float4*)ap)[i];
    float4 xv = ((const float4*)xws)[i];
    a.x = fmaxf(d * (a.x + xv.x) + b.x, 0.f);
    a.y = fmaxf(d * (a.y + xv.y) + b.y, 0.f);
    a.z = fmaxf(d * (a.z + xv.z) + b.z, 0.f);
    a.w = fmaxf(d * (a.w + xv.w) + b.w, 0.f);
    ((float4*)ap)[i] = a;
}

// ---- head: BN -> relu(z@W1+b1) -> z1@W2+b2 -> softmax ----------------------
__global__ __launch_bounds__(128) void head_kernel(
    const float* __restrict__ z, const float* __restrict__ cc,
    const float* __restrict__ gamma, const float* __restrict__ beta,
    const float* __restrict__ bmean, const float* __restrict__ bvar,
    const float* __restrict__ W1, const float* __restrict__ b1,
    const float* __restrict__ W2, const float* __restrict__ b2,
    float* __restrict__ out)
{
    __shared__ float zb[512];
    __shared__ float z1[128];
    __shared__ float lg[10];
    __shared__ float red[2];
    int b = blockIdx.x, t = threadIdx.x;
    float ccb = cc[b];
    for (int k = t; k < 512; k += 128) {
        float v = z[(long)b * 512 + k];
        if (k >= 256 && k < 384) v /= ccb;                 // mean pool
        v = (v - bmean[k]) * rsqrtf(bvar[k] + 1e-5f) * gamma[k] + beta[k];
        zb[k] = v;
    }
    __syncthreads();
    float acc = b1[t];
    for (int k = 0; k < 512; ++k) acc += zb[k] * W1[k * 128 + t];
    z1[t] = fmaxf(acc, 0.f);
    __syncthreads();
    if (t < 10) {
        float a = b2[t];
        for (int k = 0; k < 128; ++k) a += z1[k] * W2[k * 10 + t];
        lg[t] = a;
    }
    __syncthreads();
    if (t == 0) {
        float m = lg[0];
        for (int i = 1; i < 10; ++i) m = fmaxf(m, lg[i]);
        float s = 0.f;
        for (int i = 0; i < 10; ++i) s += expf(lg[i] - m);
        red[0] = m; red[1] = s;
    }
    __syncthreads();
    if (t < 10) out[(long)b * 10 + t] = expf(lg[t] - red[0]) / red[1];
}

// ---------------------------------------------------------------------------
extern "C" void kernel_launch(void* const* d_in, const int* in_sizes, int n_in,
                              void* d_out, int out_size, void* d_ws, size_t ws_size,
                              hipStream_t stream)
{
    const float* x      = (const float*)d_in[0];
    const int*   ei     = (const int*)  d_in[1];
    const float* wts    = (const float*)d_in[2];
    const int*   batch  = (const int*)  d_in[3];
    const int*   cnodes = (const int*)  d_in[4];
    const int*   cclus  = (const int*)  d_in[5];
    const int*   cbatch = (const int*)  d_in[6];
    const float* Win    = (const float*)d_in[7];
    const float* bin    = (const float*)d_in[8];
    const float* Wblk   = (const float*)d_in[9];
    const float* bblk   = (const float*)d_in[10];
    const float* gma    = (const float*)d_in[11];
    const float* bta    = (const float*)d_in[12];
    const float* bmean  = (const float*)d_in[13];
    const float* bvar   = (const float*)d_in[14];
    const float* W1     = (const float*)d_in[15];
    const float* b1     = (const float*)d_in[16];
    const float* W2     = (const float*)d_in[17];
    const float* b2     = (const float*)d_in[18];
    float* out = (float*)d_out;

    const int N  = in_sizes[0] / H;
    const int E  = in_sizes[1] / 2;
    const int M  = in_sizes[4];
    const int KC = in_sizes[6];
    const int Bq = out_size / 10;

    const int* src = ei;
    const int* dst = ei + E;

    float* ws = (float*)d_ws;
    const long NH = (long)N * H;
    const long KH = (long)KC * H;
    float* A    = ws;            // xw, later zn            [NH]
    float* Bb   = A + NH;        // agg/h, later ye         [NH]
    float* C    = Bb + NH;       // x_add, later ap/hp      [KH]
    float* D    = C + KH;        // x_max                   [KH]
    float* Ebuf = D + KH;        // xw_p / xws              [KH]
    float* deg  = Ebuf + KH;     // deg -> dinv             [N]
    float* zn1  = deg + N;       //                         [N]
    float* ye1  = zn1 + N;       //                         [N]
    float* degp = ye1 + N;       // degp -> dinvp           [KC]
    float* z    = degp + KC;     // pooled features         [Bq*512]
    float* cc   = z + (long)Bq * 512;  // cluster counts    [Bq]

    // zero small accumulators (deg, zn1, ye1, degp, z, cc are contiguous)
    hipMemsetAsync(deg, 0, (3L * N + KC + (long)Bq * 512 + Bq) * sizeof(float), stream);

    // 1. weighted degree + dinv
    deg_edges<<<(E + 255) / 256, 256, 0, stream>>>(dst, wts, deg, E);
    rsqrt_inplace<<<(N + 255) / 256, 256, 0, stream>>>(deg, N);

    // 2. xw = x @ W_in
    gemm128<<<(N + 63) / 64, 256, 0, stream>>>(x, Win, A, N, nullptr, 0);

    // 3. conv_in: agg = dinv^2*xw + sum_msgs; h = relu(agg + b_in)
    agg_init<<<(int)((NH / 4 + 255) / 256), 256, 0, stream>>>(A, deg, Bb, NH / 4);
    edge_msg<<<(E + 7) / 8, 256, 0, stream>>>(src, dst, wts, deg, A, Bb, E, 1);
    relu_bias<<<(int)((NH / 4 + 255) / 256), 256, 0, stream>>>(Bb, bin, NH / 4);

    // 4. global pools of h + cover pools
    hipMemsetAsync(C, 0, 2 * KH * sizeof(float), stream);   // x_add, x_max
    pair_msg<<<(M + 7) / 8, 256, 0, stream>>>(cnodes, cclus, Bb, C, D, M);
    seg_pool<<<1024, 128, 0, stream>>>(Bb, batch, z, N, 0, 128);
    hist64<<<256, 256, 0, stream>>>(cbatch, cc, KC);

    // 5. degp = aprime(ones) + 1 -> dinvp
    zn1_pairs<<<(M + 255) / 256, 256, 0, stream>>>(cnodes, zn1, M);
    ye1_edges<<<(E + 255) / 256, 256, 0, stream>>>(src, dst, wts, zn1, ye1, E);
    degp_pairs<<<(M + 255) / 256, 256, 0, stream>>>(cnodes, cclus, ye1, degp, M);
    rsqrt_inplace<<<(KC + 255) / 256, 256, 0, stream>>>(degp, KC);

    // 6. xws = dinvp * (x_add @ Wblk_top + x_max @ Wblk_bot)
    gemm128<<<(KC + 63) / 64, 256, 0, stream>>>(C, Wblk, Ebuf, KC, nullptr, 0);
    gemm128<<<(KC + 63) / 64, 256, 0, stream>>>(D, Wblk + 128 * 128, Ebuf, KC, degp, 1);

    // 7. aprime(xws): zn (A) -> ye (Bb) -> ap (C)
    hipMemsetAsync(A, 0, NH * sizeof(float), stream);
    pair_msg<<<(M + 7) / 8, 256, 0, stream>>>(cclus, cnodes, Ebuf, A, nullptr, M);
    hipMemsetAsync(Bb, 0, NH * sizeof(float), stream);
    edge_msg<<<(E + 7) / 8, 256, 0, stream>>>(src, dst, wts, nullptr, A, Bb, E, 0);
    hipMemsetAsync(C, 0, KH * sizeof(float), stream);
    pair_msg<<<(M + 7) / 8, 256, 0, stream>>>(cnodes, cclus, Bb, C, nullptr, M);

    // 8. hp = relu(dinvp * (ap + xws) + b_blk)   (in place over C)
    hp_kernel<<<(int)((KH / 4 + 255) / 256), 256, 0, stream>>>(C, Ebuf, degp, bblk, KH / 4);

    // 9. cluster pools of hp (sum -> mean later, max)
    seg_pool<<<512, 128, 0, stream>>>(C, cbatch, z, KC, 256, 384);

    // 10. head: BN -> MLP -> softmax
    head_kernel<<<Bq, 128, 0, stream>>>(z, cc, gma, bta, bmean, bvar, W1, b1, W2, b2, out);
}

// Round 2
// 6813.654 us; speedup vs baseline: 1.0008x; 1.0008x over previous
//
#include <hip/hip_runtime.h>

// ---------------------------------------------------------------------------
// KPlexPool: GCN -> pools -> matrix-free pooled GCN -> MLP head + softmax
// Sizes: N=100000, E=1600000, H=128, M=150000, KC=60000, B=64, C_OUT=10
// ---------------------------------------------------------------------------

#define H 128

__device__ __forceinline__ void atomAddF(float* p, float v) {
    unsafeAtomicAdd(p, v);   // global_atomic_add_f32 on gfx950
}
__device__ __forceinline__ void atomMaxPos(float* p, float v) {
    // valid for non-negative floats (bit pattern order == numeric order)
    atomicMax(reinterpret_cast<int*>(p), __float_as_int(v));
}

// ---- degree accumulation: deg[dst[e]] += w[e] ------------------------------
__global__ void deg_edges(const int* __restrict__ dst, const float* __restrict__ w,
                          float* __restrict__ deg, int E) {
    int e = blockIdx.x * blockDim.x + threadIdx.x;
    if (e < E) atomAddF(&deg[dst[e]], w[e]);
}

// ---- x = rsqrt(x + 1) ------------------------------------------------------
__global__ void rsqrt_inplace(float* __restrict__ p, int n) {
    int i = blockIdx.x * blockDim.x + threadIdx.x;
    if (i < n) p[i] = rsqrtf(p[i] + 1.0f);
}

// ---- GEMM: Out[r][c] (+)= rowscale[r] * sum_k X[r][k] * W[k][c],  K=128 ----
// 64 rows x 128 cols per block, 256 threads, thread = 4 rows x 8 cols.
// W (64KB) staged in LDS; X rows read through L1 (broadcast within lane group).
__global__ __launch_bounds__(256) void gemm128(
    const float* __restrict__ X, const float* __restrict__ W,
    float* __restrict__ Out, int nrows,
    const float* __restrict__ rowscale, int accumulate)
{
    __shared__ float Wl[128 * 128];
    int t = threadIdx.x;
    for (int i = t; i < 4096; i += 256)
        ((float4*)Wl)[i] = ((const float4*)W)[i];
    __syncthreads();

    int cgrp = t & 15;          // 16 col groups of 8 cols
    int rgrp = t >> 4;          // 16 row groups of 4 rows
    long rb = (long)blockIdx.x * 64 + rgrp * 4;
    long nm1 = (long)nrows - 1;
    const float* xr0 = X + (rb + 0 < nm1 ? rb + 0 : nm1) * H;
    const float* xr1 = X + (rb + 1 < nm1 ? rb + 1 : nm1) * H;
    const float* xr2 = X + (rb + 2 < nm1 ? rb + 2 : nm1) * H;
    const float* xr3 = X + (rb + 3 < nm1 ? rb + 3 : nm1) * H;

    float acc[4][8];
#pragma unroll
    for (int i = 0; i < 4; ++i)
#pragma unroll
        for (int j = 0; j < 8; ++j) acc[i][j] = 0.f;

    for (int k = 0; k < 128; ++k) {
        float4 w0 = ((float4*)Wl)[k * 32 + cgrp * 2];
        float4 w1 = ((float4*)Wl)[k * 32 + cgrp * 2 + 1];
        float xv0 = xr0[k], xv1 = xr1[k], xv2 = xr2[k], xv3 = xr3[k];
        acc[0][0] += xv0 * w0.x; acc[0][1] += xv0 * w0.y; acc[0][2] += xv0 * w0.z; acc[0][3] += xv0 * w0.w;
        acc[0][4] += xv0 * w1.x; acc[0][5] += xv0 * w1.y; acc[0][6] += xv0 * w1.z; acc[0][7] += xv0 * w1.w;
        acc[1][0] += xv1 * w0.x; acc[1][1] += xv1 * w0.y; acc[1][2] += xv1 * w0.z; acc[1][3] += xv1 * w0.w;
        acc[1][4] += xv1 * w1.x; acc[1][5] += xv1 * w1.y; acc[1][6] += xv1 * w1.z; acc[1][7] += xv1 * w1.w;
        acc[2][0] += xv2 * w0.x; acc[2][1] += xv2 * w0.y; acc[2][2] += xv2 * w0.z; acc[2][3] += xv2 * w0.w;
        acc[2][4] += xv2 * w1.x; acc[2][5] += xv2 * w1.y; acc[2][6] += xv2 * w1.z; acc[2][7] += xv2 * w1.w;
        acc[3][0] += xv3 * w0.x; acc[3][1] += xv3 * w0.y; acc[3][2] += xv3 * w0.z; acc[3][3] += xv3 * w0.w;
        acc[3][4] += xv3 * w1.x; acc[3][5] += xv3 * w1.y; acc[3][6] += xv3 * w1.z; acc[3][7] += xv3 * w1.w;
    }

#pragma unroll
    for (int i = 0; i < 4; ++i) {
        long gr = rb + i;
        if (gr >= nrows) continue;
        float* o = Out + gr * H + cgrp * 8;
        float4 o0 = make_float4(acc[i][0], acc[i][1], acc[i][2], acc[i][3]);
        float4 o1 = make_float4(acc[i][4], acc[i][5], acc[i][6], acc[i][7]);
        if (accumulate) {
            float4 p0 = ((float4*)o)[0], p1 = ((float4*)o)[1];
            o0.x += p0.x; o0.y += p0.y; o0.z += p0.z; o0.w += p0.w;
            o1.x += p1.x; o1.y += p1.y; o1.z += p1.z; o1.w += p1.w;
        }
        if (rowscale) {
            float s = rowscale[gr];
            o0.x *= s; o0.y *= s; o0.z *= s; o0.w *= s;
            o1.x *= s; o1.y *= s; o1.z *= s; o1.w *= s;
        }
        ((float4*)o)[0] = o0;
        ((float4*)o)[1] = o1;
    }
}

// ---- agg[n][:] = dinv[n]^2 * xw[n][:]  (float4 granularity) ----------------
__global__ void agg_init(const float* __restrict__ xw, const float* __restrict__ dinv,
                         float* __restrict__ agg, long n4) {
    long i = (long)blockIdx.x * blockDim.x + threadIdx.x;
    if (i >= n4) return;
    float d = dinv[i >> 5];
    float dd = d * d;
    float4 v = ((const float4*)xw)[i];
    ((float4*)agg)[i] = make_float4(dd * v.x, dd * v.y, dd * v.z, dd * v.w);
}

// ---- per edge: Acc[dst] += scale * X[src], scale = w (*dinv[s]*dinv[d]) ----
// 32 lanes / edge, float4 per lane
__global__ __launch_bounds__(256) void edge_msg(
    const int* __restrict__ src, const int* __restrict__ dst,
    const float* __restrict__ w, const float* __restrict__ dinv,
    const float* __restrict__ X, float* __restrict__ Acc, int E, int use_dinv)
{
    int e = blockIdx.x * 8 + (threadIdx.x >> 5);
    if (e >= E) return;
    int lane = threadIdx.x & 31;
    int s = src[e], d = dst[e];
    float sc = w[e];
    if (use_dinv) sc *= dinv[s] * dinv[d];
    float4 v = *(const float4*)(X + (long)s * H + lane * 4);
    float* o = Acc + (long)d * H + lane * 4;
    atomAddF(o + 0, sc * v.x);
    atomAddF(o + 1, sc * v.y);
    atomAddF(o + 2, sc * v.z);
    atomAddF(o + 3, sc * v.w);
}

// ---- h = relu(h + bias) ----------------------------------------------------
__global__ void relu_bias(float* __restrict__ h, const float* __restrict__ bias, long n4) {
    long i = (long)blockIdx.x * blockDim.x + threadIdx.x;
    if (i >= n4) return;
    float4 b = ((const float4*)bias)[i & 31];
    float4 v = ((float4*)h)[i];
    v.x = fmaxf(v.x + b.x, 0.f); v.y = fmaxf(v.y + b.y, 0.f);
    v.z = fmaxf(v.z + b.z, 0.f); v.w = fmaxf(v.w + b.w, 0.f);
    ((float4*)h)[i] = v;
}

// ---- per pair: Aadd[idst] += X[isrc]; Amax[idst] = max(.., X[isrc]) --------
__global__ __launch_bounds__(256) void pair_msg(
    const int* __restrict__ isrc, const int* __restrict__ idst,
    const float* __restrict__ X, float* __restrict__ Aadd,
    float* __restrict__ Amax, int M)
{
    int p = blockIdx.x * 8 + (threadIdx.x >> 5);
    if (p >= M) return;
    int lane = threadIdx.x & 31;
    int s = isrc[p], d = idst[p];
    float4 v = *(const float4*)(X + (long)s * H + lane * 4);
    float* o = Aadd + (long)d * H + lane * 4;
    atomAddF(o + 0, v.x); atomAddF(o + 1, v.y);
    atomAddF(o + 2, v.z); atomAddF(o + 3, v.w);
    if (Amax) {
        float* om = Amax + (long)d * H + lane * 4;
        atomMaxPos(om + 0, v.x); atomMaxPos(om + 1, v.y);
        atomMaxPos(om + 2, v.z); atomMaxPos(om + 3, v.w);
    }
}

// ---- sorted-segment pool: sums + maxes of X rows into Z[b*512 + off + j] ---
// seg is sorted; one block handles a contiguous chunk of rows, thread = col.
__global__ __launch_bounds__(128) void seg_pool(
    const float* __restrict__ X, const int* __restrict__ seg,
    float* __restrict__ Z, int n, int sumoff, int maxoff)
{
    int j = threadIdx.x;
    long beg = (long)blockIdx.x * n / gridDim.x;
    long end = (long)(blockIdx.x + 1) * n / gridDim.x;
    if (beg >= end) return;
    int curb = seg[beg];
    float s = 0.f, mx = 0.f;
    for (long i = beg; i < end; ++i) {
        int b = seg[i];
        if (b != curb) {
            atomAddF(&Z[(long)curb * 512 + sumoff + j], s);
            atomMaxPos(&Z[(long)curb * 512 + maxoff + j], mx);
            s = 0.f; mx = 0.f; curb = b;
        }
        float v = X[i * (long)H + j];
        s += v; mx = fmaxf(mx, v);
    }
    atomAddF(&Z[(long)curb * 512 + sumoff + j], s);
    atomMaxPos(&Z[(long)curb * 512 + maxoff + j], mx);
}

// ---- histogram of seg values into cc (float counts) ------------------------
__global__ void hist64(const int* __restrict__ seg, float* __restrict__ cc, int n) {
    __shared__ int hc[128];
    if (threadIdx.x < 128) hc[threadIdx.x] = 0;
    __syncthreads();
    for (int i = blockIdx.x * blockDim.x + threadIdx.x; i < n; i += gridDim.x * blockDim.x)
        atomicAdd(&hc[seg[i]], 1);
    __syncthreads();
    if (threadIdx.x < 128 && hc[threadIdx.x] != 0)
        atomAddF(&cc[threadIdx.x], (float)hc[threadIdx.x]);
}

// ---- scalar pair/edge kernels for degp -------------------------------------
__global__ void zn1_pairs(const int* __restrict__ nodes, float* __restrict__ zn1, int M) {
    int p = blockIdx.x * blockDim.x + threadIdx.x;
    if (p < M) atomAddF(&zn1[nodes[p]], 1.0f);
}
__global__ void ye1_edges(const int* __restrict__ src, const int* __restrict__ dst,
                          const float* __restrict__ w, const float* __restrict__ zn1,
                          float* __restrict__ ye1, int E) {
    int e = blockIdx.x * blockDim.x + threadIdx.x;
    if (e < E) atomAddF(&ye1[dst[e]], w[e] * zn1[src[e]]);
}
__global__ void degp_pairs(const int* __restrict__ nodes, const int* __restrict__ clus,
                           const float* __restrict__ ye1, float* __restrict__ degp, int M) {
    int p = blockIdx.x * blockDim.x + threadIdx.x;
    if (p < M) atomAddF(&degp[clus[p]], ye1[nodes[p]]);
}

// ---- hp = relu(dinvp[r] * (ap + xws) + b_blk), in place over ap ------------
__global__ void hp_kernel(float* __restrict__ ap, const float* __restrict__ xws,
                          const float* __restrict__ dinvp, const float* __restrict__ bias,
                          long n4) {
    long i = (long)blockIdx.x * blockDim.x + threadIdx.x;
    if (i >= n4) return;
    float d = dinvp[i >> 5];
    float4 b = ((const float4*)bias)[i & 31];
    float4 a = ((float4*)ap)[i];
    float4 xv = ((const float4*)xws)[i];
    a.x = fmaxf(d * (a.x + xv.x) + b.x, 0.f);
    a.y = fmaxf(d * (a.y + xv.y) + b.y, 0.f);
    a.z = fmaxf(d * (a.z + xv.z) + b.z, 0.f);
    a.w = fmaxf(d * (a.w + xv.w) + b.w, 0.f);
    ((float4*)ap)[i] = a;
}

// ---- head: BN -> relu(z@W1+b1) -> z1@W2+b2 -> softmax ----------------------
__global__ __launch_bounds__(128) void head_kernel(
    const float* __restrict__ z, const float* __restrict__ cc,
    const float* __restrict__ gamma, const float* __restrict__ beta,
    const float* __restrict__ bmean, const float* __restrict__ bvar,
    const float* __restrict__ W1, const float* __restrict__ b1,
    const float* __restrict__ W2, const float* __restrict__ b2,
    float* __restrict__ out)
{
    __shared__ float zb[512];
    __shared__ float z1[128];
    __shared__ float lg[10];
    __shared__ float red[2];
    int b = blockIdx.x, t = threadIdx.x;
    float ccb = cc[b];
    for (int k = t; k < 512; k += 128) {
        float v = z[(long)b * 512 + k];
        if (k >= 256 && k < 384) v /= ccb;                 // mean pool
        v = (v - bmean[k]) * rsqrtf(bvar[k] + 1e-5f) * gamma[k] + beta[k];
        zb[k] = v;
    }
    __syncthreads();
    float acc = b1[t];
    for (int k = 0; k < 512; ++k) acc += zb[k] * W1[k * 128 + t];
    z1[t] = fmaxf(acc, 0.f);
    __syncthreads();
    if (t < 10) {
        float a = b2[t];
        for (int k = 0; k < 128; ++k) a += z1[k] * W2[k * 10 + t];
        lg[t] = a;
    }
    __syncthreads();
    if (t == 0) {
        float m = lg[0];
        for (int i = 1; i < 10; ++i) m = fmaxf(m, lg[i]);
        float s = 0.f;
        for (int i = 0; i < 10; ++i) s += expf(lg[i] - m);
        red[0] = m; red[1] = s;
    }
    __syncthreads();
    if (t < 10) out[(long)b * 10 + t] = expf(lg[t] - red[0]) / red[1];
}

// ---------------------------------------------------------------------------
extern "C" void kernel_launch(void* const* d_in, const int* in_sizes, int n_in,
                              void* d_out, int out_size, void* d_ws, size_t ws_size,
                              hipStream_t stream)
{
    const float* x      = (const float*)d_in[0];
    const int*   ei     = (const int*)  d_in[1];
    const float* wts    = (const float*)d_in[2];
    const int*   batch  = (const int*)  d_in[3];
    const int*   cnodes = (const int*)  d_in[4];
    const int*   cclus  = (const int*)  d_in[5];
    const int*   cbatch = (const int*)  d_in[6];
    const float* Win    = (const float*)d_in[7];
    const float* bin    = (const float*)d_in[8];
    const float* Wblk   = (const float*)d_in[9];
    const float* bblk   = (const float*)d_in[10];
    const float* gma    = (const float*)d_in[11];
    const float* bta    = (const float*)d_in[12];
    const float* bmean  = (const float*)d_in[13];
    const float* bvar   = (const float*)d_in[14];
    const float* W1     = (const float*)d_in[15];
    const float* b1     = (const float*)d_in[16];
    const float* W2     = (const float*)d_in[17];
    const float* b2     = (const float*)d_in[18];
    float* out = (float*)d_out;

    const int N  = in_sizes[0] / H;
    const int E  = in_sizes[1] / 2;
    const int M  = in_sizes[4];
    const int KC = in_sizes[6];
    const int Bq = out_size / 10;

    const int* src = ei;
    const int* dst = ei + E;

    float* ws = (float*)d_ws;
    const long NH = (long)N * H;
    const long KH = (long)KC * H;
    float* A    = ws;            // xw, later zn            [NH]
    float* Bb   = A + NH;        // agg/h, later ye         [NH]
    float* C    = Bb + NH;       // x_add, later ap/hp      [KH]
    float* D    = C + KH;        // x_max                   [KH]
    float* Ebuf = D + KH;        // xw_p / xws              [KH]
    float* deg  = Ebuf + KH;     // deg -> dinv             [N]
    float* zn1  = deg + N;       //                         [N]
    float* ye1  = zn1 + N;       //                         [N]
    float* degp = ye1 + N;       // degp -> dinvp           [KC]
    float* z    = degp + KC;     // pooled features         [Bq*512]
    float* cc   = z + (long)Bq * 512;  // cluster counts    [Bq]

    // zero small accumulators (deg, zn1, ye1, degp, z, cc are contiguous)
    hipMemsetAsync(deg, 0, (3L * N + KC + (long)Bq * 512 + Bq) * sizeof(float), stream);

    // 1. weighted degree + dinv
    deg_edges<<<(E + 255) / 256, 256, 0, stream>>>(dst, wts, deg, E);
    rsqrt_inplace<<<(N + 255) / 256, 256, 0, stream>>>(deg, N);

    // 2. xw = x @ W_in
    gemm128<<<(N + 63) / 64, 256, 0, stream>>>(x, Win, A, N, nullptr, 0);

    // 3. conv_in: agg = dinv^2*xw + sum_msgs; h = relu(agg + b_in)
    agg_init<<<(int)((NH / 4 + 255) / 256), 256, 0, stream>>>(A, deg, Bb, NH / 4);
    edge_msg<<<(E + 7) / 8, 256, 0, stream>>>(src, dst, wts, deg, A, Bb, E, 1);
    relu_bias<<<(int)((NH / 4 + 255) / 256), 256, 0, stream>>>(Bb, bin, NH / 4);

    // 4. global pools of h + cover pools
    hipMemsetAsync(C, 0, 2 * KH * sizeof(float), stream);   // x_add, x_max
    pair_msg<<<(M + 7) / 8, 256, 0, stream>>>(cnodes, cclus, Bb, C, D, M);
    seg_pool<<<1024, 128, 0, stream>>>(Bb, batch, z, N, 0, 128);
    hist64<<<256, 256, 0, stream>>>(cbatch, cc, KC);

    // 5. degp = aprime(ones) + 1 -> dinvp
    zn1_pairs<<<(M + 255) / 256, 256, 0, stream>>>(cnodes, zn1, M);
    ye1_edges<<<(E + 255) / 256, 256, 0, stream>>>(src, dst, wts, zn1, ye1, E);
    degp_pairs<<<(M + 255) / 256, 256, 0, stream>>>(cnodes, cclus, ye1, degp, M);
    rsqrt_inplace<<<(KC + 255) / 256, 256, 0, stream>>>(degp, KC);

    // 6. xws = dinvp * (x_add @ Wblk_top + x_max @ Wblk_bot)
    gemm128<<<(KC + 63) / 64, 256, 0, stream>>>(C, Wblk, Ebuf, KC, nullptr, 0);
    gemm128<<<(KC + 63) / 64, 256, 0, stream>>>(D, Wblk + 128 * 128, Ebuf, KC, degp, 1);

    // 7. aprime(xws): zn (A) -> ye (Bb) -> ap (C)
    hipMemsetAsync(A, 0, NH * sizeof(float), stream);
    pair_msg<<<(M + 7) / 8, 256, 0, stream>>>(cclus, cnodes, Ebuf, A, nullptr, M);
    hipMemsetAsync(Bb, 0, NH * sizeof(float), stream);
    edge_msg<<<(E + 7) / 8, 256, 0, stream>>>(src, dst, wts, nullptr, A, Bb, E, 0);
    hipMemsetAsync(C, 0, KH * sizeof(float), stream);
    pair_msg<<<(M + 7) / 8, 256, 0, stream>>>(cnodes, cclus, Bb, C, nullptr, M);

    // 8. hp = relu(dinvp * (ap + xws) + b_blk)   (in place over C)
    hp_kernel<<<(int)((KH / 4 + 255) / 256), 256, 0, stream>>>(C, Ebuf, degp, bblk, KH / 4);

    // 9. cluster pools of hp (sum -> mean later, max)
    seg_pool<<<512, 128, 0, stream>>>(C, cbatch, z, KC, 256, 384);

    // 10. head: BN -> MLP -> softmax
    head_kernel<<<Bq, 128, 0, stream>>>(z, cc, gma, bta, bmean, bvar, W1, b1, W2, b2, out);
}

// Round 3
// 6810.808 us; speedup vs baseline: 1.0012x; 1.0004x over previous
//
#include <hip/hip_runtime.h>

// ---------------------------------------------------------------------------
// KPlexPool: GCN -> pools -> matrix-free pooled GCN -> MLP head + softmax
// Sizes: N=100000, E=1600000, H=128, M=150000, KC=60000, B=64, C_OUT=10
// ---------------------------------------------------------------------------

#define H 128

__device__ __forceinline__ void atomAddF(float* p, float v) {
    unsafeAtomicAdd(p, v);   // global_atomic_add_f32 on gfx950
}
__device__ __forceinline__ void atomMaxPos(float* p, float v) {
    // valid for non-negative floats (bit pattern order == numeric order)
    atomicMax(reinterpret_cast<int*>(p), __float_as_int(v));
}

// ---- degree accumulation: deg[dst[e]] += w[e] ------------------------------
__global__ void deg_edges(const int* __restrict__ dst, const float* __restrict__ w,
                          float* __restrict__ deg, int E) {
    int e = blockIdx.x * blockDim.x + threadIdx.x;
    if (e < E) atomAddF(&deg[dst[e]], w[e]);
}

// ---- x = rsqrt(x + 1) ------------------------------------------------------
__global__ void rsqrt_inplace(float* __restrict__ p, int n) {
    int i = blockIdx.x * blockDim.x + threadIdx.x;
    if (i < n) p[i] = rsqrtf(p[i] + 1.0f);
}

// ---- GEMM: Out[r][c] (+)= rowscale[r] * sum_k X[r][k] * W[k][c],  K=128 ----
// 64 rows x 128 cols per block, 256 threads, thread = 4 rows x 8 cols.
// W (64KB) staged in LDS; X rows read through L1 (broadcast within lane group).
__global__ __launch_bounds__(256) void gemm128(
    const float* __restrict__ X, const float* __restrict__ W,
    float* __restrict__ Out, int nrows,
    const float* __restrict__ rowscale, int accumulate)
{
    __shared__ float Wl[128 * 128];
    int t = threadIdx.x;
    for (int i = t; i < 4096; i += 256)
        ((float4*)Wl)[i] = ((const float4*)W)[i];
    __syncthreads();

    int cgrp = t & 15;          // 16 col groups of 8 cols
    int rgrp = t >> 4;          // 16 row groups of 4 rows
    long rb = (long)blockIdx.x * 64 + rgrp * 4;
    long nm1 = (long)nrows - 1;
    const float* xr0 = X + (rb + 0 < nm1 ? rb + 0 : nm1) * H;
    const float* xr1 = X + (rb + 1 < nm1 ? rb + 1 : nm1) * H;
    const float* xr2 = X + (rb + 2 < nm1 ? rb + 2 : nm1) * H;
    const float* xr3 = X + (rb + 3 < nm1 ? rb + 3 : nm1) * H;

    float acc[4][8];
#pragma unroll
    for (int i = 0; i < 4; ++i)
#pragma unroll
        for (int j = 0; j < 8; ++j) acc[i][j] = 0.f;

    for (int k = 0; k < 128; ++k) {
        float4 w0 = ((float4*)Wl)[k * 32 + cgrp * 2];
        float4 w1 = ((float4*)Wl)[k * 32 + cgrp * 2 + 1];
        float xv0 = xr0[k], xv1 = xr1[k], xv2 = xr2[k], xv3 = xr3[k];
        acc[0][0] += xv0 * w0.x; acc[0][1] += xv0 * w0.y; acc[0][2] += xv0 * w0.z; acc[0][3] += xv0 * w0.w;
        acc[0][4] += xv0 * w1.x; acc[0][5] += xv0 * w1.y; acc[0][6] += xv0 * w1.z; acc[0][7] += xv0 * w1.w;
        acc[1][0] += xv1 * w0.x; acc[1][1] += xv1 * w0.y; acc[1][2] += xv1 * w0.z; acc[1][3] += xv1 * w0.w;
        acc[1][4] += xv1 * w1.x; acc[1][5] += xv1 * w1.y; acc[1][6] += xv1 * w1.z; acc[1][7] += xv1 * w1.w;
        acc[2][0] += xv2 * w0.x; acc[2][1] += xv2 * w0.y; acc[2][2] += xv2 * w0.z; acc[2][3] += xv2 * w0.w;
        acc[2][4] += xv2 * w1.x; acc[2][5] += xv2 * w1.y; acc[2][6] += xv2 * w1.z; acc[2][7] += xv2 * w1.w;
        acc[3][0] += xv3 * w0.x; acc[3][1] += xv3 * w0.y; acc[3][2] += xv3 * w0.z; acc[3][3] += xv3 * w0.w;
        acc[3][4] += xv3 * w1.x; acc[3][5] += xv3 * w1.y; acc[3][6] += xv3 * w1.z; acc[3][7] += xv3 * w1.w;
    }

#pragma unroll
    for (int i = 0; i < 4; ++i) {
        long gr = rb + i;
        if (gr >= nrows) continue;
        float* o = Out + gr * H + cgrp * 8;
        float4 o0 = make_float4(acc[i][0], acc[i][1], acc[i][2], acc[i][3]);
        float4 o1 = make_float4(acc[i][4], acc[i][5], acc[i][6], acc[i][7]);
        if (accumulate) {
            float4 p0 = ((float4*)o)[0], p1 = ((float4*)o)[1];
            o0.x += p0.x; o0.y += p0.y; o0.z += p0.z; o0.w += p0.w;
            o1.x += p1.x; o1.y += p1.y; o1.z += p1.z; o1.w += p1.w;
        }
        if (rowscale) {
            float s = rowscale[gr];
            o0.x *= s; o0.y *= s; o0.z *= s; o0.w *= s;
            o1.x *= s; o1.y *= s; o1.z *= s; o1.w *= s;
        }
        ((float4*)o)[0] = o0;
        ((float4*)o)[1] = o1;
    }
}

// ---- agg[n][:] = dinv[n]^2 * xw[n][:]  (float4 granularity) ----------------
__global__ void agg_init(const float* __restrict__ xw, const float* __restrict__ dinv,
                         float* __restrict__ agg, long n4) {
    long i = (long)blockIdx.x * blockDim.x + threadIdx.x;
    if (i >= n4) return;
    float d = dinv[i >> 5];
    float dd = d * d;
    float4 v = ((const float4*)xw)[i];
    ((float4*)agg)[i] = make_float4(dd * v.x, dd * v.y, dd * v.z, dd * v.w);
}

// ---- per edge: Acc[dst] += scale * X[src], scale = w (*dinv[s]*dinv[d]) ----
// 32 lanes / edge, float4 per lane
__global__ __launch_bounds__(256) void edge_msg(
    const int* __restrict__ src, const int* __restrict__ dst,
    const float* __restrict__ w, const float* __restrict__ dinv,
    const float* __restrict__ X, float* __restrict__ Acc, int E, int use_dinv)
{
    int e = blockIdx.x * 8 + (threadIdx.x >> 5);
    if (e >= E) return;
    int lane = threadIdx.x & 31;
    int s = src[e], d = dst[e];
    float sc = w[e];
    if (use_dinv) sc *= dinv[s] * dinv[d];
    float4 v = *(const float4*)(X + (long)s * H + lane * 4);
    float* o = Acc + (long)d * H + lane * 4;
    atomAddF(o + 0, sc * v.x);
    atomAddF(o + 1, sc * v.y);
    atomAddF(o + 2, sc * v.z);
    atomAddF(o + 3, sc * v.w);
}

// ---- h = relu(h + bias) ----------------------------------------------------
__global__ void relu_bias(float* __restrict__ h, const float* __restrict__ bias, long n4) {
    long i = (long)blockIdx.x * blockDim.x + threadIdx.x;
    if (i >= n4) return;
    float4 b = ((const float4*)bias)[i & 31];
    float4 v = ((float4*)h)[i];
    v.x = fmaxf(v.x + b.x, 0.f); v.y = fmaxf(v.y + b.y, 0.f);
    v.z = fmaxf(v.z + b.z, 0.f); v.w = fmaxf(v.w + b.w, 0.f);
    ((float4*)h)[i] = v;
}

// ---- per pair: Aadd[idst] += X[isrc]; Amax[idst] = max(.., X[isrc]) --------
__global__ __launch_bounds__(256) void pair_msg(
    const int* __restrict__ isrc, const int* __restrict__ idst,
    const float* __restrict__ X, float* __restrict__ Aadd,
    float* __restrict__ Amax, int M)
{
    int p = blockIdx.x * 8 + (threadIdx.x >> 5);
    if (p >= M) return;
    int lane = threadIdx.x & 31;
    int s = isrc[p], d = idst[p];
    float4 v = *(const float4*)(X + (long)s * H + lane * 4);
    float* o = Aadd + (long)d * H + lane * 4;
    atomAddF(o + 0, v.x); atomAddF(o + 1, v.y);
    atomAddF(o + 2, v.z); atomAddF(o + 3, v.w);
    if (Amax) {
        float* om = Amax + (long)d * H + lane * 4;
        atomMaxPos(om + 0, v.x); atomMaxPos(om + 1, v.y);
        atomMaxPos(om + 2, v.z); atomMaxPos(om + 3, v.w);
    }
}

// ---- sorted-segment pool: sums + maxes of X rows into Z[b*512 + off + j] ---
// seg is sorted; one block handles a contiguous chunk of rows, thread = col.
__global__ __launch_bounds__(128) void seg_pool(
    const float* __restrict__ X, const int* __restrict__ seg,
    float* __restrict__ Z, int n, int sumoff, int maxoff)
{
    int j = threadIdx.x;
    long beg = (long)blockIdx.x * n / gridDim.x;
    long end = (long)(blockIdx.x + 1) * n / gridDim.x;
    if (beg >= end) return;
    int curb = seg[beg];
    float s = 0.f, mx = 0.f;
    for (long i = beg; i < end; ++i) {
        int b = seg[i];
        if (b != curb) {
            atomAddF(&Z[(long)curb * 512 + sumoff + j], s);
            atomMaxPos(&Z[(long)curb * 512 + maxoff + j], mx);
            s = 0.f; mx = 0.f; curb = b;
        }
        float v = X[i * (long)H + j];
        s += v; mx = fmaxf(mx, v);
    }
    atomAddF(&Z[(long)curb * 512 + sumoff + j], s);
    atomMaxPos(&Z[(long)curb * 512 + maxoff + j], mx);
}

// ---- histogram of seg values into cc (float counts) ------------------------
__global__ void hist64(const int* __restrict__ seg, float* __restrict__ cc, int n) {
    __shared__ int hc[128];
    if (threadIdx.x < 128) hc[threadIdx.x] = 0;
    __syncthreads();
    for (int i = blockIdx.x * blockDim.x + threadIdx.x; i < n; i += gridDim.x * blockDim.x)
        atomicAdd(&hc[seg[i]], 1);
    __syncthreads();
    if (threadIdx.x < 128 && hc[threadIdx.x] != 0)
        atomAddF(&cc[threadIdx.x], (float)hc[threadIdx.x]);
}

// ---- scalar pair/edge kernels for degp -------------------------------------
__global__ void zn1_pairs(const int* __restrict__ nodes, float* __restrict__ zn1, int M) {
    int p = blockIdx.x * blockDim.x + threadIdx.x;
    if (p < M) atomAddF(&zn1[nodes[p]], 1.0f);
}
__global__ void ye1_edges(const int* __restrict__ src, const int* __restrict__ dst,
                          const float* __restrict__ w, const float* __restrict__ zn1,
                          float* __restrict__ ye1, int E) {
    int e = blockIdx.x * blockDim.x + threadIdx.x;
    if (e < E) atomAddF(&ye1[dst[e]], w[e] * zn1[src[e]]);
}
__global__ void degp_pairs(const int* __restrict__ nodes, const int* __restrict__ clus,
                           const float* __restrict__ ye1, float* __restrict__ degp, int M) {
    int p = blockIdx.x * blockDim.x + threadIdx.x;
    if (p < M) atomAddF(&degp[clus[p]], ye1[nodes[p]]);
}

// ---- hp = relu(dinvp[r] * (ap + xws) + b_blk), in place over ap ------------
__global__ void hp_kernel(float* __restrict__ ap, const float* __restrict__ xws,
                          const float* __restrict__ dinvp, const float* __restrict__ bias,
                          long n4) {
    long i = (long)blockIdx.x * blockDim.x + threadIdx.x;
    if (i >= n4) return;
    float d = dinvp[i >> 5];
    float4 b = ((const float4*)bias)[i & 31];
    float4 a = ((float4*)ap)[i];
    float4 xv = ((const float4*)xws)[i];
    a.x = fmaxf(d * (a.x + xv.x) + b.x, 0.f);
    a.y = fmaxf(d * (a.y + xv.y) + b.y, 0.f);
    a.z = fmaxf(d * (a.z + xv.z) + b.z, 0.f);
    a.w = fmaxf(d * (a.w + xv.w) + b.w, 0.f);
    ((float4*)ap)[i] = a;
}

// ---- head: BN -> relu(z@W1+b1) -> z1@W2+b2 -> softmax ----------------------
__global__ __launch_bounds__(128) void head_kernel(
    const float* __restrict__ z, const float* __restrict__ cc,
    const float* __restrict__ gamma, const float* __restrict__ beta,
    const float* __restrict__ bmean, const float* __restrict__ bvar,
    const float* __restrict__ W1, const float* __restrict__ b1,
    const float* __restrict__ W2, const float* __restrict__ b2,
    float* __restrict__ out)
{
    __shared__ float zb[512];
    __shared__ float z1[128];
    __shared__ float lg[10];
    __shared__ float red[2];
    int b = blockIdx.x, t = threadIdx.x;
    float ccb = cc[b];
    for (int k = t; k < 512; k += 128) {
        float v = z[(long)b * 512 + k];
        if (k >= 256 && k < 384) v /= ccb;                 // mean pool
        v = (v - bmean[k]) * rsqrtf(bvar[k] + 1e-5f) * gamma[k] + beta[k];
        zb[k] = v;
    }
    __syncthreads();
    float acc = b1[t];
    for (int k = 0; k < 512; ++k) acc += zb[k] * W1[k * 128 + t];
    z1[t] = fmaxf(acc, 0.f);
    __syncthreads();
    if (t < 10) {
        float a = b2[t];
        for (int k = 0; k < 128; ++k) a += z1[k] * W2[k * 10 + t];
        lg[t] = a;
    }
    __syncthreads();
    if (t == 0) {
        float m = lg[0];
        for (int i = 1; i < 10; ++i) m = fmaxf(m, lg[i]);
        float s = 0.f;
        for (int i = 0; i < 10; ++i) s += expf(lg[i] - m);
        red[0] = m; red[1] = s;
    }
    __syncthreads();
    if (t < 10) out[(long)b * 10 + t] = expf(lg[t] - red[0]) / red[1];
}

// ---------------------------------------------------------------------------
extern "C" void kernel_launch(void* const* d_in, const int* in_sizes, int n_in,
                              void* d_out, int out_size, void* d_ws, size_t ws_size,
                              hipStream_t stream)
{
    const float* x      = (const float*)d_in[0];
    const int*   ei     = (const int*)  d_in[1];
    const float* wts    = (const float*)d_in[2];
    const int*   batch  = (const int*)  d_in[3];
    const int*   cnodes = (const int*)  d_in[4];
    const int*   cclus  = (const int*)  d_in[5];
    const int*   cbatch = (const int*)  d_in[6];
    const float* Win    = (const float*)d_in[7];
    const float* bin    = (const float*)d_in[8];
    const float* Wblk   = (const float*)d_in[9];
    const float* bblk   = (const float*)d_in[10];
    const float* gma    = (const float*)d_in[11];
    const float* bta    = (const float*)d_in[12];
    const float* bmean  = (const float*)d_in[13];
    const float* bvar   = (const float*)d_in[14];
    const float* W1     = (const float*)d_in[15];
    const float* b1     = (const float*)d_in[16];
    const float* W2     = (const float*)d_in[17];
    const float* b2     = (const float*)d_in[18];
    float* out = (float*)d_out;

    const int N  = in_sizes[0] / H;
    const int E  = in_sizes[1] / 2;
    const int M  = in_sizes[4];
    const int KC = in_sizes[6];
    const int Bq = out_size / 10;

    const int* src = ei;
    const int* dst = ei + E;

    float* ws = (float*)d_ws;
    const long NH = (long)N * H;
    const long KH = (long)KC * H;
    float* A    = ws;            // xw, later zn            [NH]
    float* Bb   = A + NH;        // agg/h, later ye         [NH]
    float* C    = Bb + NH;       // x_add, later ap/hp      [KH]
    float* D    = C + KH;        // x_max                   [KH]
    float* Ebuf = D + KH;        // xw_p / xws              [KH]
    float* deg  = Ebuf + KH;     // deg -> dinv             [N]
    float* zn1  = deg + N;       //                         [N]
    float* ye1  = zn1 + N;       //                         [N]
    float* degp = ye1 + N;       // degp -> dinvp           [KC]
    float* z    = degp + KC;     // pooled features         [Bq*512]
    float* cc   = z + (long)Bq * 512;  // cluster counts    [Bq]

    // zero small accumulators (deg, zn1, ye1, degp, z, cc are contiguous)
    hipMemsetAsync(deg, 0, (3L * N + KC + (long)Bq * 512 + Bq) * sizeof(float), stream);

    // 1. weighted degree + dinv
    deg_edges<<<(E + 255) / 256, 256, 0, stream>>>(dst, wts, deg, E);
    rsqrt_inplace<<<(N + 255) / 256, 256, 0, stream>>>(deg, N);

    // 2. xw = x @ W_in
    gemm128<<<(N + 63) / 64, 256, 0, stream>>>(x, Win, A, N, nullptr, 0);

    // 3. conv_in: agg = dinv^2*xw + sum_msgs; h = relu(agg + b_in)
    agg_init<<<(int)((NH / 4 + 255) / 256), 256, 0, stream>>>(A, deg, Bb, NH / 4);
    edge_msg<<<(E + 7) / 8, 256, 0, stream>>>(src, dst, wts, deg, A, Bb, E, 1);
    relu_bias<<<(int)((NH / 4 + 255) / 256), 256, 0, stream>>>(Bb, bin, NH / 4);

    // 4. global pools of h + cover pools
    hipMemsetAsync(C, 0, 2 * KH * sizeof(float), stream);   // x_add, x_max
    pair_msg<<<(M + 7) / 8, 256, 0, stream>>>(cnodes, cclus, Bb, C, D, M);
    seg_pool<<<1024, 128, 0, stream>>>(Bb, batch, z, N, 0, 128);
    hist64<<<256, 256, 0, stream>>>(cbatch, cc, KC);

    // 5. degp = aprime(ones) + 1 -> dinvp
    zn1_pairs<<<(M + 255) / 256, 256, 0, stream>>>(cnodes, zn1, M);
    ye1_edges<<<(E + 255) / 256, 256, 0, stream>>>(src, dst, wts, zn1, ye1, E);
    degp_pairs<<<(M + 255) / 256, 256, 0, stream>>>(cnodes, cclus, ye1, degp, M);
    rsqrt_inplace<<<(KC + 255) / 256, 256, 0, stream>>>(degp, KC);

    // 6. xws = dinvp * (x_add @ Wblk_top + x_max @ Wblk_bot)
    gemm128<<<(KC + 63) / 64, 256, 0, stream>>>(C, Wblk, Ebuf, KC, nullptr, 0);
    gemm128<<<(KC + 63) / 64, 256, 0, stream>>>(D, Wblk + 128 * 128, Ebuf, KC, degp, 1);

    // 7. aprime(xws): zn (A) -> ye (Bb) -> ap (C)
    hipMemsetAsync(A, 0, NH * sizeof(float), stream);
    pair_msg<<<(M + 7) / 8, 256, 0, stream>>>(cclus, cnodes, Ebuf, A, nullptr, M);
    hipMemsetAsync(Bb, 0, NH * sizeof(float), stream);
    edge_msg<<<(E + 7) / 8, 256, 0, stream>>>(src, dst, wts, nullptr, A, Bb, E, 0);
    hipMemsetAsync(C, 0, KH * sizeof(float), stream);
    pair_msg<<<(M + 7) / 8, 256, 0, stream>>>(cnodes, cclus, Bb, C, nullptr, M);

    // 8. hp = relu(dinvp * (ap + xws) + b_blk)   (in place over C)
    hp_kernel<<<(int)((KH / 4 + 255) / 256), 256, 0, stream>>>(C, Ebuf, degp, bblk, KH / 4);

    // 9. cluster pools of hp (sum -> mean later, max)
    seg_pool<<<512, 128, 0, stream>>>(C, cbatch, z, KC, 256, 384);

    // 10. head: BN -> MLP -> softmax
    head_kernel<<<Bq, 128, 0, stream>>>(z, cc, gma, bta, bmean, bvar, W1, b1, W2, b2, out);
}